// Round 3
// baseline (779.688 us; speedup 1.0000x reference)
//
#include <hip/hip_runtime.h>

typedef __attribute__((ext_vector_type(8))) short short8;   // 8 bf16 (MFMA A/B frag)
typedef __attribute__((ext_vector_type(4))) float f32x4;    // MFMA C/D frag

#define MFMA16(a, b, c) __builtin_amdgcn_mfma_f32_16x16x32_bf16((a), (b), (c), 0, 0, 0)

// fp32 -> bf16 RNE
static __device__ inline short f2bf(float x) {
    union { float f; unsigned u; } v;
    v.f = x;
    unsigned r = v.u + 0x7fffu + ((v.u >> 16) & 1u);
    return (short)(r >> 16);
}

static __device__ inline short8 pack_frag(float4 v0, float4 v1) {
    short8 a;
    a[0] = f2bf(v0.x); a[1] = f2bf(v0.y); a[2] = f2bf(v0.z); a[3] = f2bf(v0.w);
    a[4] = f2bf(v1.x); a[5] = f2bf(v1.y); a[6] = f2bf(v1.z); a[7] = f2bf(v1.w);
    return a;
}

// B=512, E=4, N=256, F=64
// out[b,n,g] = sum_e adj[b,e] @ (node[b] @ W_e + b_e) + node[b] @ W_add + b_add
// Grid 1024: block bb -> batch b = bb>>1, m-half mh = bb&1 (C rows 128*mh..+127).
// LDS 43008 B -> 3 blocks/CU; adj K-loop is barrier-free, direct global->reg.
__global__ __launch_bounds__(256, 3) void gconv_kernel(
    const float* __restrict__ node,    // [512,256,64]
    const float* __restrict__ adj,     // [512,4,256,256]
    const float* __restrict__ W_edge,  // [4,64,64]
    const float* __restrict__ b_edge,  // [4,64]
    const float* __restrict__ W_add,   // [64,64]
    const float* __restrict__ b_add,   // [64]
    float* __restrict__ out)           // [512,256,64]
{
    __shared__ short hiddenT[64][264];   // hidden_e^T [g][k]   33792 B
    __shared__ short wT[64][72];         // weight^T [g][f]      9216 B  (total 43008)

    const int bb   = blockIdx.x;
    const int b    = bb >> 1;
    const int mh   = bb & 1;        // which 128-row half of C this block owns
    const int t    = threadIdx.x;
    const int lane = t & 63;
    const int w    = t >> 6;
    const int col  = lane & 15;     // A-row / B-col / D-col in 16-tile
    const int kq   = lane >> 4;     // k-offset 8*kq; D-rows 4*kq..4*kq+3

    const float* nodeB = node + (size_t)b * (256 * 64);

    // ---- node A-frags for hidden compute: full 256 rows, wave w owns 64w.. ----
    short8 anode[4][2];
    #pragma unroll
    for (int rt = 0; rt < 4; ++rt)
        #pragma unroll
        for (int h = 0; h < 2; ++h) {
            const float* p = nodeB + (64 * w + 16 * rt + col) * 64 + 32 * h + 8 * kq;
            anode[rt][h] = pack_frag(*(const float4*)p, *(const float4*)(p + 4));
        }

    // ---- node A-frags for the residual: this block's 128-row half ----
    short8 ares[2][2];
    #pragma unroll
    for (int rt = 0; rt < 2; ++rt)
        #pragma unroll
        for (int h = 0; h < 2; ++h) {
            const float* p = nodeB + (128 * mh + 32 * w + 16 * rt + col) * 64 + 32 * h + 8 * kq;
            ares[rt][h] = pack_frag(*(const float4*)p, *(const float4*)(p + 4));
        }

    // ---- stage W_add^T -> wT ----
    #pragma unroll
    for (int i = 0; i < 16; ++i) {
        int idx = i * 256 + t;
        wT[idx & 63][idx >> 6] = f2bf(W_add[idx]);
    }
    __syncthreads();

    // ---- residual: acc = node[half] @ W_add ----
    f32x4 acc[2][4];
    {
        const f32x4 zf = {0.f, 0.f, 0.f, 0.f};
        #pragma unroll
        for (int rt = 0; rt < 2; ++rt)
            #pragma unroll
            for (int ct = 0; ct < 4; ++ct)
                acc[rt][ct] = zf;
        #pragma unroll
        for (int h = 0; h < 2; ++h) {
            short8 bfr[4];
            #pragma unroll
            for (int ct = 0; ct < 4; ++ct)
                bfr[ct] = *(const short8*)&wT[16 * ct + col][32 * h + 8 * kq];
            #pragma unroll
            for (int rt = 0; rt < 2; ++rt)
                #pragma unroll
                for (int ct = 0; ct < 4; ++ct)
                    acc[rt][ct] = MFMA16(ares[rt][h], bfr[ct], acc[rt][ct]);
        }
    }
    __syncthreads();    // wT reads done before e-loop restage

    for (int e = 0; e < 4; ++e) {
        // ---- stage W_edge[e]^T -> wT ----
        const float* We = W_edge + e * (64 * 64);
        #pragma unroll
        for (int i = 0; i < 16; ++i) {
            int idx = i * 256 + t;
            wT[idx & 63][idx >> 6] = f2bf(We[idx]);
        }
        __syncthreads();

        // ---- hidden_e = node @ W_e + b_e  -> hiddenT[g][k] bf16 (full 256 k) ----
        #pragma unroll
        for (int rt = 0; rt < 4; ++rt) {
            #pragma unroll
            for (int ct = 0; ct < 4; ++ct) {
                short8 b0 = *(const short8*)&wT[16 * ct + col][8 * kq];
                short8 b1 = *(const short8*)&wT[16 * ct + col][32 + 8 * kq];
                f32x4 h = {0.f, 0.f, 0.f, 0.f};
                h = MFMA16(anode[rt][0], b0, h);
                h = MFMA16(anode[rt][1], b1, h);
                float bias = b_edge[e * 64 + 16 * ct + col];
                short4 s;
                s.x = f2bf(h.x + bias); s.y = f2bf(h.y + bias);
                s.z = f2bf(h.z + bias); s.w = f2bf(h.w + bias);
                *(short4*)&hiddenT[16 * ct + col][64 * w + 16 * rt + 4 * kq] = s;
            }
        }
        __syncthreads();

        // ---- acc += adj[b,e,half] @ hidden_e : barrier-free, double-buffered ----
        const float* adjE = adj + ((size_t)(b * 4 + e)) * (256 * 256)
                                + (size_t)(128 * mh) * 256;
        float4 cur[2][2], nxt[2][2];
        #pragma unroll
        for (int rt = 0; rt < 2; ++rt) {
            const float* p = adjE + (32 * w + 16 * rt + col) * 256 + 8 * kq;
            cur[rt][0] = *(const float4*)p;
            cur[rt][1] = *(const float4*)(p + 4);
        }
        for (int ks = 0; ks < 8; ++ks) {
            if (ks < 7) {
                #pragma unroll
                for (int rt = 0; rt < 2; ++rt) {
                    const float* p = adjE + (32 * w + 16 * rt + col) * 256
                                   + (ks + 1) * 32 + 8 * kq;
                    nxt[rt][0] = *(const float4*)p;
                    nxt[rt][1] = *(const float4*)(p + 4);
                }
            }
            short8 bfrag[4];
            #pragma unroll
            for (int ct = 0; ct < 4; ++ct)
                bfrag[ct] = *(const short8*)&hiddenT[16 * ct + col][ks * 32 + 8 * kq];
            #pragma unroll
            for (int rt = 0; rt < 2; ++rt) {
                short8 a = pack_frag(cur[rt][0], cur[rt][1]);
                #pragma unroll
                for (int ct = 0; ct < 4; ++ct)
                    acc[rt][ct] = MFMA16(a, bfrag[ct], acc[rt][ct]);
            }
            #pragma unroll
            for (int rt = 0; rt < 2; ++rt) {
                cur[rt][0] = nxt[rt][0];
                cur[rt][1] = nxt[rt][1];
            }
        }
        __syncthreads();    // hiddenT/wT reads done before next e overwrites
    }

    // ---- epilogue: out = acc + b_add ----
    float* outB = out + (size_t)b * (256 * 64);
    #pragma unroll
    for (int ct = 0; ct < 4; ++ct) {
        float bias = b_add[16 * ct + col];
        #pragma unroll
        for (int rt = 0; rt < 2; ++rt) {
            int row = 128 * mh + 32 * w + 16 * rt + 4 * kq;
            #pragma unroll
            for (int r = 0; r < 4; ++r)
                outB[(size_t)(row + r) * 64 + 16 * ct + col] = acc[rt][ct][r] + bias;
        }
    }
}

extern "C" void kernel_launch(void* const* d_in, const int* in_sizes, int n_in,
                              void* d_out, int out_size, void* d_ws, size_t ws_size,
                              hipStream_t stream) {
    const float* node   = (const float*)d_in[0];
    const float* adj    = (const float*)d_in[1];
    const float* W_edge = (const float*)d_in[2];
    const float* b_edge = (const float*)d_in[3];
    const float* W_add  = (const float*)d_in[4];
    const float* b_add  = (const float*)d_in[5];
    float* out = (float*)d_out;

    gconv_kernel<<<dim3(1024), dim3(256), 0, stream>>>(
        node, adj, W_edge, b_edge, W_add, b_add, out);
}